// Round 16
// baseline (327.773 us; speedup 1.0000x reference)
//
#include <hip/hip_runtime.h>
#include <hip/hip_bf16.h>
#include <cstddef>
#include <cstdint>

#define DM 512
#define DS 64
#define L_SEQ 8192
#define NB 8
#define M_ROWS (NB * L_SEQ)      // 65536
#define LN_EPS 1e-3f
#define NCHUNK 256
#define LCH 32                   // NCHUNK * LCH == L_SEQ

typedef __attribute__((ext_vector_type(8))) short short8;
typedef __attribute__((ext_vector_type(4))) float f32x4;
using bf16 = __hip_bfloat16;
using ushort_t = unsigned short;

__device__ __forceinline__ unsigned short f2bf(float f) {
    bf16 h = __float2bfloat16(f);
    return *reinterpret_cast<unsigned short*>(&h);
}

// B-operand MFMA fragment packing: element (k, n) of a KxN weight ->
// pk[((n16*Kd32 + kt)*64 + fq*16 + fr)*8 + e]; one wave fragment = 1 KB contig.
__device__ __forceinline__ size_t pkidx(int k, int n, int Kd32) {
    int n16 = n >> 4, fr = n & 15, kt = k >> 5, fq = (k >> 3) & 3, e = k & 7;
    return (((size_t)(n16 * Kd32 + kt) * 64 + fq * 16 + fr) << 3) + e;
}

__device__ __forceinline__ void gload_lds16(const void* g, void* l) {
    __builtin_amdgcn_global_load_lds(
        (const __attribute__((address_space(1))) void*)g,
        (__attribute__((address_space(3))) void*)l, 16, 0, 0);
}

// ---------------- wprep: composite weights computed directly into packed bf16 --
// Wc3[k][n] = sum_c W_in[k][c]*D[c]*W_out[c][n]   (512x512, packed Kd32=16)
// Wc1[k][n] = sum_c W_in[k][c]*W_xs[c][n]         (512x64,  packed Kd32=16)
// Wc2[s][n] = sum_c W_so[s][c]*W_out[c][n]        (64x512,  packed Kd32=2)
// bc2[n]    = b_out[n] + sum_c b_in[c]*D[c]*W_out[c][n]
// bc1[n]    = sum_c b_in[c]*W_xs[c][n]
__global__ __launch_bounds__(256) void wprep(const float* __restrict__ W_so,
                                             const float* __restrict__ W_out,
                                             const float* __restrict__ W_in,
                                             const float* __restrict__ W_xs,
                                             const float* __restrict__ b_in,
                                             const float* __restrict__ b_out,
                                             const float* __restrict__ Dv,
                                             ushort_t* __restrict__ Wc3Pk,
                                             ushort_t* __restrict__ Wc1Pk,
                                             ushort_t* __restrict__ Wc2Pk,
                                             float* __restrict__ bc1,
                                             float* __restrict__ bc2)
{
    int i = blockIdx.x * 256 + threadIdx.x;
    if (i < 262144) {
        int k = i >> 9, n = i & 511;
        float a = 0.f;
        for (int c = 0; c < 512; ++c) a += W_in[k * 512 + c] * Dv[c] * W_out[c * 512 + n];
        Wc3Pk[pkidx(k, n, 16)] = f2bf(a);
    } else if (i < 294912) {
        int j = i - 262144; int k = j >> 6, n = j & 63;
        float a = 0.f;
        for (int c = 0; c < 512; ++c) a += W_in[k * 512 + c] * W_xs[c * 64 + n];
        Wc1Pk[pkidx(k, n, 16)] = f2bf(a);
    } else if (i < 327680) {
        int j = i - 294912; int s = j >> 9, n = j & 511;
        float a = 0.f;
        for (int c = 0; c < 512; ++c) a += W_so[s * 512 + c] * W_out[c * 512 + n];
        Wc2Pk[pkidx(s, n, 2)] = f2bf(a);
    } else if (i < 328192) {
        int n = i - 327680;
        float a = b_out[n];
        for (int c = 0; c < 512; ++c) a += b_in[c] * Dv[c] * W_out[c * 512 + n];
        bc2[n] = a;
    } else if (i < 328256) {
        int n = i - 328192;
        float a = 0.f;
        for (int c = 0; c < 512; ++c) a += b_in[c] * W_xs[c * 64 + n];
        bc1[n] = a;
    }
}

// ---------------- fused LayerNorm + xs-GEMM (r15, unchanged) ----------------
__global__ __launch_bounds__(256) void ln_xs(const float* __restrict__ x,
                                             const float* __restrict__ gamma,
                                             const float* __restrict__ beta,
                                             const ushort_t* __restrict__ Wc1Pk,
                                             const float* __restrict__ bc1,
                                             ushort_t* __restrict__ xn,
                                             float* __restrict__ xs)
{
    __shared__ ushort_t xt[16 * 512];     // 16 KB
    const int tid = threadIdx.x;
    const int lane = tid & 63, w = tid >> 6;
    const int fr = lane & 15, fq = lane >> 4;
    const size_t row0 = (size_t)blockIdx.x * 16;

    const float4* g4 = (const float4*)gamma;
    const float4* b4 = (const float4*)beta;
    float4 g0 = g4[lane * 2], g1 = g4[lane * 2 + 1];
    float4 bb0 = b4[lane * 2], bb1 = b4[lane * 2 + 1];

    #pragma unroll
    for (int rr = 0; rr < 4; ++rr) {
        int r = w * 4 + rr;
        size_t row = row0 + r;
        const float4* xr = (const float4*)(x + row * DM);
        float4 v0 = xr[lane * 2], v1 = xr[lane * 2 + 1];
        float s  = v0.x + v0.y + v0.z + v0.w + v1.x + v1.y + v1.z + v1.w;
        float s2 = v0.x*v0.x + v0.y*v0.y + v0.z*v0.z + v0.w*v0.w
                 + v1.x*v1.x + v1.y*v1.y + v1.z*v1.z + v1.w*v1.w;
        #pragma unroll
        for (int off = 32; off > 0; off >>= 1) {
            s  += __shfl_xor(s,  off);
            s2 += __shfl_xor(s2, off);
        }
        float mu  = s * (1.0f / DM);
        float var = s2 * (1.0f / DM) - mu * mu;
        float rs  = rsqrtf(var + LN_EPS);
        short8 o;
        o[0] = (short)f2bf((v0.x - mu) * rs * g0.x + bb0.x);
        o[1] = (short)f2bf((v0.y - mu) * rs * g0.y + bb0.y);
        o[2] = (short)f2bf((v0.z - mu) * rs * g0.z + bb0.z);
        o[3] = (short)f2bf((v0.w - mu) * rs * g0.w + bb0.w);
        o[4] = (short)f2bf((v1.x - mu) * rs * g1.x + bb1.x);
        o[5] = (short)f2bf((v1.y - mu) * rs * g1.y + bb1.y);
        o[6] = (short)f2bf((v1.z - mu) * rs * g1.z + bb1.z);
        o[7] = (short)f2bf((v1.w - mu) * rs * g1.w + bb1.w);
        int g = (lane & 7) ^ ((int)row & 7);
        *(short8*)(xn + row * DM + (lane >> 3) * 64 + g * 8) = o;     // global (GD)
        *(short8*)&xt[r * 512 + (lane >> 3) * 64 + g * 8] = o;        // LDS tile
    }
    __syncthreads();

    // xs = xn @ Wc1 + bc1 for cols w*16..w*16+15
    f32x4 acc = (f32x4){0.f, 0.f, 0.f, 0.f};
    #pragma unroll
    for (int kt = 0; kt < 16; ++kt) {
        int seg = kt >> 1;
        int gk = ((kt & 1) * 4 + fq) ^ (fr & 7);
        short8 af = *(const short8*)&xt[fr * 512 + seg * 64 + gk * 8];
        short8 bf = *(const short8*)(Wc1Pk + (((size_t)(w * 16 + kt) * 64 + lane) << 3));
        acc = __builtin_amdgcn_mfma_f32_16x16x32_bf16(af, bf, acc, 0, 0, 0);
    }
    float bv = bc1[w * 16 + fr];
    #pragma unroll
    for (int r2 = 0; r2 < 4; ++r2)
        xs[(row0 + fq * 4 + r2) * DS + w * 16 + fr] = acc[r2] + bv;
}

// ---------------- SSM scan ----------------
__device__ __forceinline__ void ssm_params(const float* A_log, const float* log_delta,
                                           const float* Bv, int n, float& Ab, float& Bb)
{
    float A  = -expf(A_log[n]);
    float dl = log1pf(expf(log_delta[n]));   // softplus
    float dA2 = dl * A * 0.5f;
    float inv = 1.0f / (1.0f - dA2);
    Ab = (1.0f + dA2) * inv;
    Bb = dl * inv * Bv[n];
}

__global__ __launch_bounds__(64) void scan_pass1(const float* __restrict__ xs,
                                                 const float* __restrict__ A_log,
                                                 const float* __restrict__ log_delta,
                                                 const float* __restrict__ Bv,
                                                 float* __restrict__ carry)
{
    int b = blockIdx.x / NCHUNK;
    int c = blockIdx.x % NCHUNK;
    int n = threadIdx.x;
    float Ab, Bb;
    ssm_params(A_log, log_delta, Bv, n, Ab, Bb);
    size_t base = ((size_t)b * L_SEQ + (size_t)c * LCH) * DS + n;
    float h = 0.0f;
    for (int t = 0; t < LCH; ++t)
        h = Ab * h + Bb * xs[base + (size_t)t * DS];
    carry[((size_t)b * NCHUNK + c) * DS + n] = h;
}

// pass2 merged in: each block rebuilds its hin prefix from carry (<=255 FMA).
// ys written PRE-SWIZZLED (granule XOR row&7), row-major 64-col rows.
__global__ __launch_bounds__(64) void scan_pass23(const float* __restrict__ xs,
                                                  const float* __restrict__ A_log,
                                                  const float* __restrict__ log_delta,
                                                  const float* __restrict__ Bv,
                                                  const float* __restrict__ Cv,
                                                  const float* __restrict__ carry,
                                                  ushort_t* __restrict__ ys)
{
    int b = blockIdx.x / NCHUNK;
    int c = blockIdx.x % NCHUNK;
    int n = threadIdx.x;
    float Ab, Bb;
    ssm_params(A_log, log_delta, Bv, n, Ab, Bb);
    float Cn = Cv[n];
    float powL = powf(Ab, (float)LCH);
    // hin prefix (was pass2): h = sum over chunks < c
    float h = 0.0f;
    for (int cp = 0; cp < c; ++cp)
        h = powL * h + carry[((size_t)b * NCHUNK + cp) * DS + n];
    size_t base = ((size_t)b * L_SEQ + (size_t)c * LCH) * DS + n;
    size_t rowbase = ((size_t)b * L_SEQ + (size_t)c * LCH) * DS;
    for (int t = 0; t < LCH; ++t) {
        h = Ab * h + Bb * xs[base + (size_t)t * DS];
        int col = (((n >> 3) ^ (t & 7)) << 3) | (n & 7);   // row&7 == t&7
        ys[rowbase + (size_t)t * DS + col] = f2bf(Cn * h);
    }
}

// ---------------- GD: out = ys@Wc2 + xn@Wc3 + bc2 + x  (1-barrier structure) ---
// Block = 64 rows x ALL 512 cols; 8 waves, wave w owns cols w*64..+63.
// Xs tile (64 KB) via gload_lds; ys A-frags global->reg (pre-swizzled = 16B
// contiguous); B-frags streamed from L2-resident packed weights. ys loads
// issue BEFORE the gloads so their wait doesn't drain staging; ys-MFMAs run
// pre-barrier. After one __syncthreads: 256 free-running MFMAs per wave.
// 2 blocks/CU (LDS) x 8 waves = 16 waves/CU. bound (512,4): VGPR cap 128
// (est ~110; tripwire = FETCH inflation).
__global__ __launch_bounds__(512, 4) void gd_fused(const ushort_t* __restrict__ ys,
                                                   const ushort_t* __restrict__ xn,
                                                   const ushort_t* __restrict__ Wc2Pk,
                                                   const ushort_t* __restrict__ Wc3Pk,
                                                   const float* __restrict__ bc2,
                                                   const float* __restrict__ x,
                                                   float* __restrict__ out)
{
    __shared__ ushort_t Xs[64 * 512];   // 64 KB, row stride 1024 B (pre-swizzled)
    const int tid = threadIdx.x;
    const int lane = tid & 63, w = tid >> 6;
    const int fr = lane & 15, fq = lane >> 4;
    const size_t bm0 = (size_t)blockIdx.x * 64;
    const int cn0 = w * 64;
    const int n16g0 = w * 4;

    // 1) ys A-fragments + Wc2 B-fragments -> registers (issued FIRST)
    short8 ay[2][4], by[2][4];
    #pragma unroll
    for (int kt = 0; kt < 2; ++kt)
        #pragma unroll
        for (int m = 0; m < 4; ++m) {
            int row = m * 16 + fr;
            int g = (kt * 4 + fq) ^ (row & 7);
            ay[kt][m] = *(const short8*)(ys + (bm0 + row) * (size_t)64 + g * 8);
        }
    #pragma unroll
    for (int kt = 0; kt < 2; ++kt)
        #pragma unroll
        for (int n = 0; n < 4; ++n)
            by[kt][n] = *(const short8*)(Wc2Pk + (((size_t)((n16g0 + n) * 2 + kt) * 64 + lane) << 3));

    // 2) stage xn tile (9th..16th vmem ops; lane*16B linear dest)
    #pragma unroll
    for (int j = 0; j < 8; ++j) {
        int row = j * 8 + w;
        gload_lds16(xn + (bm0 + row) * (size_t)512 + lane * 8,
                    &Xs[(size_t)j * 4096 + w * 512]);
    }

    // 3) ys MFMAs pre-barrier (wait only on ay/by; gloads stay in flight)
    f32x4 acc[4][4];
    #pragma unroll
    for (int m = 0; m < 4; ++m)
        #pragma unroll
        for (int n = 0; n < 4; ++n)
            acc[m][n] = (f32x4){0.f, 0.f, 0.f, 0.f};
    #pragma unroll
    for (int kt = 0; kt < 2; ++kt)
        #pragma unroll
        for (int m = 0; m < 4; ++m)
            #pragma unroll
            for (int n = 0; n < 4; ++n)
                acc[m][n] = __builtin_amdgcn_mfma_f32_16x16x32_bf16(ay[kt][m], by[kt][n], acc[m][n], 0, 0, 0);

    __syncthreads();    // drains gloads; Xs ready

    // 4) xn @ Wc3: 16 K-slices, free-running (no barriers)
    #pragma unroll
    for (int kt = 0; kt < 16; ++kt) {
        short8 af[4], bf[4];
        #pragma unroll
        for (int m = 0; m < 4; ++m) {
            int row = m * 16 + fr;
            int G = kt * 4 + fq;
            int gi = (G & ~7) | ((G & 7) ^ (row & 7));
            af[m] = *(const short8*)&Xs[row * 512 + gi * 8];
        }
        #pragma unroll
        for (int n = 0; n < 4; ++n)
            bf[n] = *(const short8*)(Wc3Pk + (((size_t)((n16g0 + n) * 16 + kt) * 64 + lane) << 3));
        #pragma unroll
        for (int m = 0; m < 4; ++m)
            #pragma unroll
            for (int n = 0; n < 4; ++n)
                acc[m][n] = __builtin_amdgcn_mfma_f32_16x16x32_bf16(af[m], bf[n], acc[m][n], 0, 0, 0);
    }

    // 5) epilogue: + bc2 + x residual
    #pragma unroll
    for (int n = 0; n < 4; ++n) {
        int colg = cn0 + n * 16 + fr;
        float bv = bc2[colg];
        #pragma unroll
        for (int m = 0; m < 4; ++m) {
            size_t row = bm0 + m * 16 + fq * 4;
            #pragma unroll
            for (int r = 0; r < 4; ++r) {
                size_t idx = (row + r) * (size_t)DM + colg;
                out[idx] = acc[m][n][r] + bv + x[idx];
            }
        }
    }
}

// ---------------- launcher ----------------
extern "C" void kernel_launch(void* const* d_in, const int* in_sizes, int n_in,
                              void* d_out, int out_size, void* d_ws, size_t ws_size,
                              hipStream_t stream)
{
    const float* x         = (const float*)d_in[0];
    const float* ln_gamma  = (const float*)d_in[1];
    const float* ln_beta   = (const float*)d_in[2];
    const float* W_in      = (const float*)d_in[3];
    const float* b_in      = (const float*)d_in[4];
    const float* W_xs      = (const float*)d_in[5];
    const float* A_log     = (const float*)d_in[6];
    const float* log_delta = (const float*)d_in[7];
    const float* Bv        = (const float*)d_in[8];
    const float* Cv        = (const float*)d_in[9];
    const float* Dv        = (const float*)d_in[10];
    const float* W_so      = (const float*)d_in[11];
    const float* W_out     = (const float*)d_in[12];
    const float* b_out     = (const float*)d_in[13];
    float* out = (float*)d_out;

    const size_t M = M_ROWS;
    float*    xs_f   = (float*)d_ws;                         // M*64 f32
    ushort_t* xn_b   = (ushort_t*)(xs_f + M * DS);           // M*512 bf16
    ushort_t* ys_b   = xn_b + M * (size_t)DM;                // M*64 bf16
    ushort_t* Wc3Pk  = ys_b + M * (size_t)DS;                // 512*512
    ushort_t* Wc1Pk  = Wc3Pk + (size_t)DM * DM;              // 512*64
    ushort_t* Wc2Pk  = Wc1Pk + (size_t)DM * DS;              // 64*512
    float*    bc1    = (float*)(Wc2Pk + (size_t)DS * DM);    // 64
    float*    bc2    = bc1 + 64;                             // 512
    float*    carry  = bc2 + DM;                             // 8*256*64

    // composite weights -> packed bf16 directly (prep+pack merged)
    wprep<<<dim3(1283), dim3(256), 0, stream>>>(W_so, W_out, W_in, W_xs, b_in, b_out, Dv,
                                                Wc3Pk, Wc1Pk, Wc2Pk, bc1, bc2);
    // fused LN + xs-GEMM
    ln_xs<<<dim3((unsigned)(M / 16)), dim3(256), 0, stream>>>(x, ln_gamma, ln_beta,
                                                              Wc1Pk, bc1, xn_b, xs_f);
    // scan (pass2 merged into pass3)
    scan_pass1<<<dim3(NB * NCHUNK), dim3(64), 0, stream>>>(xs_f, A_log, log_delta, Bv, carry);
    scan_pass23<<<dim3(NB * NCHUNK), dim3(64), 0, stream>>>(xs_f, A_log, log_delta, Bv, Cv,
                                                            carry, ys_b);
    // GD: out = ys@Wc2 + xn@Wc3 + bc2 + x  (1-barrier fused structure)
    gd_fused<<<dim3((unsigned)(M / 64)), dim3(512), 0, stream>>>(ys_b, xn_b, Wc2Pk, Wc3Pk,
                                                                 bc2, x, out);
}